// Round 14
// baseline (14.393 us; speedup 1.0000x reference)
//
#include <hip/hip_runtime.h>

#define EPSV 1e-7f

// v16: v13/v15 (13.8us, best) + per-wave X-channel ROTATION -- the last
// zero-cost probe. Theory: the 4 co-resident waves/SIMD run identical inst
// streams launched together => all hit the same load-wait simultaneously =>
// TLP is phase-aligned into uselessness (explains why more waves (v8),
// prefetch shuffles (v11/v12) were all null). Rotating the X-phase channel
// order per wave (c = (cc+rot)%3, rot = (swz+waveid)%3) decorrelates the 3
// X-burst stalls at zero reg/inst cost; channel sum is commutative (+-ulp).
// Pre-commit: <=13.45 => correlation confirmed, pursue stagger; 13.5-14.0 =>
// neutral, declare floor next round; >=14.1 => revert & declare.
typedef float f2 __attribute__((ext_vector_type(2)));

__global__ __launch_bounds__(256) void matting_loss_kernel(
    const float* __restrict__ outp, const float* __restrict__ cont,
    float* __restrict__ ws)
{
    const int H = 512, W = 512, NW = 510;
    const int HW = H * W;

    // --- XCD swizzle (bijective: 1024 % 8 == 0); 2 XCDs per image. ---
    const int lin = blockIdx.x + 8 * (blockIdx.y + 32 * blockIdx.z);
    const int swz = (lin & 7) * 128 + (lin >> 3);
    const int b   = swz >> 8;                       // image 0..3
    const int rem = swz & 255;
    const int gx  = (rem & 7) * 32 + threadIdx.x;   // 0..255 -> wx0 = 2*gx
    const int gg  = (rem >> 3) * 8 + threadIdx.y;   // 0..255 -> wy0 = 2*gg
    const int wx0 = gx * 2;
    const int wy0 = gg * 2;

    const int tid  = threadIdx.y * 32 + threadIdx.x;
    const int rot  = (swz + (tid >> 6)) % 3;        // per-wave channel rotation

    const float* Cin = cont + (size_t)b * 3 * HW;
    const float* Xin = outp + (size_t)b * 3 * HW;

    float contrib = 0.0f;
    const float inv9 = 1.0f / 9.0f;

#define WSUM(OUT, A0, A1) { f2 T_ = (A0) + (A1); (OUT).x = T_.x + (A0).y; (OUT).y = T_.y + (A1).x; }
#define CSUM(CH, R0, OUT) { \
    f2 A0_ = Cb[CH][R0][0] + Cb[CH][R0+1][0] + Cb[CH][R0+2][0]; \
    f2 A1_ = Cb[CH][R0][1] + Cb[CH][R0+1][1] + Cb[CH][R0+2][1]; \
    WSUM(OUT, A0_, A1_) }
#define CDOT(CA, CB_, R0, OUT) { \
    f2 A0_ = Cb[CA][R0][0]*Cb[CB_][R0][0] + Cb[CA][R0+1][0]*Cb[CB_][R0+1][0] + Cb[CA][R0+2][0]*Cb[CB_][R0+2][0]; \
    f2 A1_ = Cb[CA][R0][1]*Cb[CB_][R0][1] + Cb[CA][R0+1][1]*Cb[CB_][R0+1][1] + Cb[CA][R0+2][1]*Cb[CB_][R0+2][1]; \
    WSUM(OUT, A0_, A1_) }
#define XSUM(R0, OUT) { \
    f2 A0_ = Xb[R0][0] + Xb[R0+1][0] + Xb[R0+2][0]; \
    f2 A1_ = Xb[R0][1] + Xb[R0+1][1] + Xb[R0+2][1]; \
    WSUM(OUT, A0_, A1_) }
#define XXDOT(R0, OUT) { \
    f2 A0_ = Xb[R0][0]*Xb[R0][0] + Xb[R0+1][0]*Xb[R0+1][0] + Xb[R0+2][0]*Xb[R0+2][0]; \
    f2 A1_ = Xb[R0][1]*Xb[R0][1] + Xb[R0+1][1]*Xb[R0+1][1] + Xb[R0+2][1]*Xb[R0+2][1]; \
    WSUM(OUT, A0_, A1_) }
#define XCDOT(R0, K_, OUT) { \
    f2 A0_ = Xb[R0][0]*Cb[K_][R0][0] + Xb[R0+1][0]*Cb[K_][R0+1][0] + Xb[R0+2][0]*Cb[K_][R0+2][0]; \
    f2 A1_ = Xb[R0][1]*Cb[K_][R0][1] + Xb[R0+1][1]*Cb[K_][R0+1][1] + Xb[R0+2][1]*Cb[K_][R0+2][1]; \
    WSUM(OUT, A0_, A1_) }

    if (wy0 < NW && wx0 < NW) {   // windows wy0,wy0+1 x wx0,wx0+1 all valid
        const int base = wy0 * W + wx0;

        // Load burst: 24 C f2 (3ch x 4 rows x 2 pairs); latency under moments.
        f2 Cb[3][4][2];
        #pragma unroll
        for (int ch = 0; ch < 3; ++ch)
            #pragma unroll
            for (int r = 0; r < 4; ++r) {
                const float* p = Cin + ch * HW + base + r * W;
                Cb[ch][r][0] = *(const f2*)p;
                Cb[ch][r][1] = *(const f2*)(p + 2);
            }

        // --- Moment phase, both window-rows (rows wr..wr+2) ---
        f2 mu0[2], mu1[2], mu2[2];
        f2 adj0[2], adj1[2], adj2[2], adj3[2], adj4[2], adj5[2], idet[2];
        #pragma unroll
        for (int wr = 0; wr < 2; ++wr) {
            f2 sI0, sI1, sI2, s00, s01, s02, s11, s12, s22;
            CSUM(0, wr, sI0) CSUM(1, wr, sI1) CSUM(2, wr, sI2)
            CDOT(0, 0, wr, s00) CDOT(0, 1, wr, s01) CDOT(0, 2, wr, s02)
            CDOT(1, 1, wr, s11) CDOT(1, 2, wr, s12) CDOT(2, 2, wr, s22)
            f2 m0 = sI0 * inv9, m1 = sI1 * inv9, m2 = sI2 * inv9;
            const float ed = EPSV * inv9;
            f2 v00 = s00 * inv9 - m0 * m0 + ed;
            f2 v01 = s01 * inv9 - m0 * m1;
            f2 v02 = s02 * inv9 - m0 * m2;
            f2 v11 = s11 * inv9 - m1 * m1 + ed;
            f2 v12 = s12 * inv9 - m1 * m2;
            f2 v22 = s22 * inv9 - m2 * m2 + ed;
            f2 a0 = v11 * v22 - v12 * v12;
            f2 a1 = v02 * v12 - v01 * v22;
            f2 a2 = v01 * v12 - v02 * v11;
            f2 det = v00 * a0 + v01 * a1 + v02 * a2;
            mu0[wr] = m0; mu1[wr] = m1; mu2[wr] = m2;
            adj0[wr] = a0; adj1[wr] = a1; adj2[wr] = a2;
            adj3[wr] = v00 * v22 - v02 * v02;
            adj4[wr] = v01 * v02 - v00 * v12;
            adj5[wr] = v00 * v11 - v01 * v01;
            f2 idv;
            idv.x = __builtin_amdgcn_rcpf(det.x);   // v_rcp_f32 (validated v3..v15)
            idv.y = __builtin_amdgcn_rcpf(det.y);
            idet[wr] = idv;
        }

        // --- X phase: per channel in WAVE-ROTATED order (decorrelates the
        // 3 load-stall phases across co-resident waves), both window-rows ---
        f2 termAcc = (f2){0.0f, 0.0f};
        #pragma unroll
        for (int cc = 0; cc < 3; ++cc) {
            int c = cc + rot;
            c = (c >= 3) ? c - 3 : c;
            f2 Xb[4][2];
            #pragma unroll
            for (int r = 0; r < 4; ++r) {
                const float* q = Xin + c * HW + base + r * W;
                Xb[r][0] = *(const f2*)q;
                Xb[r][1] = *(const f2*)(q + 2);
            }
            #pragma unroll
            for (int wr = 0; wr < 2; ++wr) {
                f2 S, SSw, W0, W1, W2;
                XSUM(wr, S) XXDOT(wr, SSw)
                XCDOT(wr, 0, W0) XCDOT(wr, 1, W1) XCDOT(wr, 2, W2)
                f2 u0 = W0 - S * mu0[wr];
                f2 u1 = W1 - S * mu1[wr];
                f2 u2 = W2 - S * mu2[wr];
                f2 qa = u0 * (adj0[wr] * u0 + adj1[wr] * u1 + adj2[wr] * u2)
                      + u1 * (adj1[wr] * u0 + adj3[wr] * u1 + adj4[wr] * u2)
                      + u2 * (adj2[wr] * u0 + adj4[wr] * u1 + adj5[wr] * u2);
                termAcc += SSw - (S * S + qa * idet[wr]) * inv9;
            }
        }
        contrib = termAcc.x + termAcc.y;   // all 4 windows valid
    }
#undef WSUM
#undef CSUM
#undef CDOT
#undef XSUM
#undef XXDOT
#undef XCDOT

    // Wave shuffle reduction -> cross-wave LDS -> ONE plain store per block.
    #pragma unroll
    for (int off = 32; off > 0; off >>= 1)
        contrib += __shfl_down(contrib, off, 64);

    __shared__ float wsum[4];
    const int lane = tid & 63, wv = tid >> 6;
    if (lane == 0) wsum[wv] = contrib;
    __syncthreads();
    if (tid == 0)
        ws[swz] = wsum[0] + wsum[1] + wsum[2] + wsum[3];
}

// Tiny reducer: image b owns ws[b*256 .. b*256+255]. Writes loss[b] directly.
__global__ __launch_bounds__(256) void reduce_kernel(
    const float* __restrict__ ws, float* __restrict__ loss)
{
    const int b = blockIdx.x;
    const int t = threadIdx.x;
    float v = ws[b * 256 + t];
    #pragma unroll
    for (int off = 32; off > 0; off >>= 1)
        v += __shfl_down(v, off, 64);

    __shared__ float s[4];
    if ((t & 63) == 0) s[t >> 6] = v;
    __syncthreads();
    if (t == 0) loss[b] = s[0] + s[1] + s[2] + s[3];
}

extern "C" void kernel_launch(void* const* d_in, const int* in_sizes, int n_in,
                              void* d_out, int out_size, void* d_ws, size_t ws_size,
                              hipStream_t stream) {
    const float* outp = (const float*)d_in[0];   // output: (4,3,512,512) f32
    const float* cont = (const float*)d_in[1];   // content: (4,3,512,512) f32
    float* loss = (float*)d_out;                 // (4,1,1) f32
    float* ws   = (float*)d_ws;                  // 1024 floats of workspace

    dim3 block(32, 8, 1);
    dim3 grid(8, 32, 4);   // 256 x-threads x 256 row-groups x 4 images
    matting_loss_kernel<<<grid, block, 0, stream>>>(outp, cont, ws);
    reduce_kernel<<<dim3(4, 1, 1), dim3(256, 1, 1), 0, stream>>>(ws, loss);
}

// Round 15
// 13.776 us; speedup vs baseline: 1.0448x; 1.0448x over previous
//
#include <hip/hip_runtime.h>

#define EPSV 1e-7f

// v17 == v13/v15 (FINAL, twice-validated 13.77/13.87us). v16's channel
// rotation regressed (+0.5us: dynamic channel addressing cost > decorrelation
// benefit, which never materialized) -- pre-commit's revert-&-declare branch.
// Session: 28.55 -> 13.8us (2.07x). Wins: atomic-tail removal (-8us, v5),
// packed-f2 math (-2.7us, v9), column factorization (-3.5us, v6), KY=2
// vertical tiling (-0.6us, v13). Nulls: occupancy 2->4, reg tier, load
// scheduling x3, XCD swizzle, rotation. Negatives: LDS staging, launch_bounds
// pins (spill cliff at min-waves>=4 on >128-reg bodies).
// Floor: HBM compulsory ~4.2us (cold inputs each iter) + issue ~2.3us +
// envelope ~2.5us + exposed-latency residual ~4-5us at the 128-VGPR-capped
// 4 waves/SIMD. All identified levers against the residual tested to null.
typedef float f2 __attribute__((ext_vector_type(2)));

__global__ __launch_bounds__(256) void matting_loss_kernel(
    const float* __restrict__ outp, const float* __restrict__ cont,
    float* __restrict__ ws)
{
    const int H = 512, W = 512, NW = 510;
    const int HW = H * W;

    // --- XCD swizzle (bijective: 1024 % 8 == 0); 2 XCDs per image. ---
    const int lin = blockIdx.x + 8 * (blockIdx.y + 32 * blockIdx.z);
    const int swz = (lin & 7) * 128 + (lin >> 3);
    const int b   = swz >> 8;                       // image 0..3
    const int rem = swz & 255;
    const int gx  = (rem & 7) * 32 + threadIdx.x;   // 0..255 -> wx0 = 2*gx
    const int gg  = (rem >> 3) * 8 + threadIdx.y;   // 0..255 -> wy0 = 2*gg
    const int wx0 = gx * 2;
    const int wy0 = gg * 2;

    const float* Cin = cont + (size_t)b * 3 * HW;
    const float* Xin = outp + (size_t)b * 3 * HW;

    float contrib = 0.0f;
    const float inv9 = 1.0f / 9.0f;

#define WSUM(OUT, A0, A1) { f2 T_ = (A0) + (A1); (OUT).x = T_.x + (A0).y; (OUT).y = T_.y + (A1).x; }
#define CSUM(CH, R0, OUT) { \
    f2 A0_ = Cb[CH][R0][0] + Cb[CH][R0+1][0] + Cb[CH][R0+2][0]; \
    f2 A1_ = Cb[CH][R0][1] + Cb[CH][R0+1][1] + Cb[CH][R0+2][1]; \
    WSUM(OUT, A0_, A1_) }
#define CDOT(CA, CB_, R0, OUT) { \
    f2 A0_ = Cb[CA][R0][0]*Cb[CB_][R0][0] + Cb[CA][R0+1][0]*Cb[CB_][R0+1][0] + Cb[CA][R0+2][0]*Cb[CB_][R0+2][0]; \
    f2 A1_ = Cb[CA][R0][1]*Cb[CB_][R0][1] + Cb[CA][R0+1][1]*Cb[CB_][R0+1][1] + Cb[CA][R0+2][1]*Cb[CB_][R0+2][1]; \
    WSUM(OUT, A0_, A1_) }
#define XSUM(R0, OUT) { \
    f2 A0_ = Xb[R0][0] + Xb[R0+1][0] + Xb[R0+2][0]; \
    f2 A1_ = Xb[R0][1] + Xb[R0+1][1] + Xb[R0+2][1]; \
    WSUM(OUT, A0_, A1_) }
#define XXDOT(R0, OUT) { \
    f2 A0_ = Xb[R0][0]*Xb[R0][0] + Xb[R0+1][0]*Xb[R0+1][0] + Xb[R0+2][0]*Xb[R0+2][0]; \
    f2 A1_ = Xb[R0][1]*Xb[R0][1] + Xb[R0+1][1]*Xb[R0+1][1] + Xb[R0+2][1]*Xb[R0+2][1]; \
    WSUM(OUT, A0_, A1_) }
#define XCDOT(R0, K_, OUT) { \
    f2 A0_ = Xb[R0][0]*Cb[K_][R0][0] + Xb[R0+1][0]*Cb[K_][R0+1][0] + Xb[R0+2][0]*Cb[K_][R0+2][0]; \
    f2 A1_ = Xb[R0][1]*Cb[K_][R0][1] + Xb[R0+1][1]*Cb[K_][R0+1][1] + Xb[R0+2][1]*Cb[K_][R0+2][1]; \
    WSUM(OUT, A0_, A1_) }

    if (wy0 < NW && wx0 < NW) {   // windows wy0,wy0+1 x wx0,wx0+1 all valid
        const int base = wy0 * W + wx0;

        // Load burst: 24 C f2 (3ch x 4 rows x 2 pairs); latency under moments.
        f2 Cb[3][4][2];
        #pragma unroll
        for (int ch = 0; ch < 3; ++ch)
            #pragma unroll
            for (int r = 0; r < 4; ++r) {
                const float* p = Cin + ch * HW + base + r * W;
                Cb[ch][r][0] = *(const f2*)p;
                Cb[ch][r][1] = *(const f2*)(p + 2);
            }

        // --- Moment phase, both window-rows (rows wr..wr+2) ---
        f2 mu0[2], mu1[2], mu2[2];
        f2 adj0[2], adj1[2], adj2[2], adj3[2], adj4[2], adj5[2], idet[2];
        #pragma unroll
        for (int wr = 0; wr < 2; ++wr) {
            f2 sI0, sI1, sI2, s00, s01, s02, s11, s12, s22;
            CSUM(0, wr, sI0) CSUM(1, wr, sI1) CSUM(2, wr, sI2)
            CDOT(0, 0, wr, s00) CDOT(0, 1, wr, s01) CDOT(0, 2, wr, s02)
            CDOT(1, 1, wr, s11) CDOT(1, 2, wr, s12) CDOT(2, 2, wr, s22)
            f2 m0 = sI0 * inv9, m1 = sI1 * inv9, m2 = sI2 * inv9;
            const float ed = EPSV * inv9;
            f2 v00 = s00 * inv9 - m0 * m0 + ed;
            f2 v01 = s01 * inv9 - m0 * m1;
            f2 v02 = s02 * inv9 - m0 * m2;
            f2 v11 = s11 * inv9 - m1 * m1 + ed;
            f2 v12 = s12 * inv9 - m1 * m2;
            f2 v22 = s22 * inv9 - m2 * m2 + ed;
            f2 a0 = v11 * v22 - v12 * v12;
            f2 a1 = v02 * v12 - v01 * v22;
            f2 a2 = v01 * v12 - v02 * v11;
            f2 det = v00 * a0 + v01 * a1 + v02 * a2;
            mu0[wr] = m0; mu1[wr] = m1; mu2[wr] = m2;
            adj0[wr] = a0; adj1[wr] = a1; adj2[wr] = a2;
            adj3[wr] = v00 * v22 - v02 * v02;
            adj4[wr] = v01 * v02 - v00 * v12;
            adj5[wr] = v00 * v11 - v01 * v01;
            f2 idv;
            idv.x = __builtin_amdgcn_rcpf(det.x);   // v_rcp_f32 (validated v3..v16)
            idv.y = __builtin_amdgcn_rcpf(det.y);
            idet[wr] = idv;
        }

        // --- X phase: per channel, 4 rows loaded once, both window-rows ---
        f2 termAcc = (f2){0.0f, 0.0f};
        #pragma unroll
        for (int c = 0; c < 3; ++c) {
            f2 Xb[4][2];
            #pragma unroll
            for (int r = 0; r < 4; ++r) {
                const float* q = Xin + c * HW + base + r * W;
                Xb[r][0] = *(const f2*)q;
                Xb[r][1] = *(const f2*)(q + 2);
            }
            #pragma unroll
            for (int wr = 0; wr < 2; ++wr) {
                f2 S, SSw, W0, W1, W2;
                XSUM(wr, S) XXDOT(wr, SSw)
                XCDOT(wr, 0, W0) XCDOT(wr, 1, W1) XCDOT(wr, 2, W2)
                f2 u0 = W0 - S * mu0[wr];
                f2 u1 = W1 - S * mu1[wr];
                f2 u2 = W2 - S * mu2[wr];
                f2 qa = u0 * (adj0[wr] * u0 + adj1[wr] * u1 + adj2[wr] * u2)
                      + u1 * (adj1[wr] * u0 + adj3[wr] * u1 + adj4[wr] * u2)
                      + u2 * (adj2[wr] * u0 + adj4[wr] * u1 + adj5[wr] * u2);
                termAcc += SSw - (S * S + qa * idet[wr]) * inv9;
            }
        }
        contrib = termAcc.x + termAcc.y;   // all 4 windows valid
    }
#undef WSUM
#undef CSUM
#undef CDOT
#undef XSUM
#undef XXDOT
#undef XCDOT

    // Wave shuffle reduction -> cross-wave LDS -> ONE plain store per block.
    #pragma unroll
    for (int off = 32; off > 0; off >>= 1)
        contrib += __shfl_down(contrib, off, 64);

    __shared__ float wsum[4];
    const int tid = threadIdx.y * 32 + threadIdx.x;
    const int lane = tid & 63, wv = tid >> 6;
    if (lane == 0) wsum[wv] = contrib;
    __syncthreads();
    if (tid == 0)
        ws[swz] = wsum[0] + wsum[1] + wsum[2] + wsum[3];
}

// Tiny reducer: image b owns ws[b*256 .. b*256+255]. Writes loss[b] directly.
__global__ __launch_bounds__(256) void reduce_kernel(
    const float* __restrict__ ws, float* __restrict__ loss)
{
    const int b = blockIdx.x;
    const int t = threadIdx.x;
    float v = ws[b * 256 + t];
    #pragma unroll
    for (int off = 32; off > 0; off >>= 1)
        v += __shfl_down(v, off, 64);

    __shared__ float s[4];
    if ((t & 63) == 0) s[t >> 6] = v;
    __syncthreads();
    if (t == 0) loss[b] = s[0] + s[1] + s[2] + s[3];
}

extern "C" void kernel_launch(void* const* d_in, const int* in_sizes, int n_in,
                              void* d_out, int out_size, void* d_ws, size_t ws_size,
                              hipStream_t stream) {
    const float* outp = (const float*)d_in[0];   // output: (4,3,512,512) f32
    const float* cont = (const float*)d_in[1];   // content: (4,3,512,512) f32
    float* loss = (float*)d_out;                 // (4,1,1) f32
    float* ws   = (float*)d_ws;                  // 1024 floats of workspace

    dim3 block(32, 8, 1);
    dim3 grid(8, 32, 4);   // 256 x-threads x 256 row-groups x 4 images
    matting_loss_kernel<<<grid, block, 0, stream>>>(outp, cont, ws);
    reduce_kernel<<<dim3(4, 1, 1), dim3(256, 1, 1), 0, stream>>>(ws, loss);
}